// Round 1
// baseline (1350.506 us; speedup 1.0000x reference)
//
#include <hip/hip_runtime.h>
#include <math.h>

// PEER layer. Selection path (sim) is computed with fp64 accumulation so our
// sim equals the correctly-rounded true value; remaining deviation vs the np
// reference is np's own fp32 GEMM rounding (~2e-7), minimizing top-k flips.
// sim is rounded to fp32 before top-k so score adds / tie semantics are
// bitwise-identical to the reference given the same sim values.
//
//  K1 fold_kernel : M[2048,1024] = keys folded into Wq   (fp64 acc, fp64 out)
//  K2 sim_kernel  : sim[1024,2048] = x @ M^T             (fp64 acc, fp32 out)
//  K3 topk_kernel : per (n,h) top16x/top16y -> staircase top16 of 256 -> softmax
//  K4 gather_kernel: g = softmax_w * gelu(x . down[row]); out = sum g * up[row]
//                   (1.07 GB HBM traffic -> the roofline floor, ~170us)
//
// This revision: LDS tiles in K1/K2 staged as double (cvt_f64_f32 once per
// element instead of once per use -> inner loop 96cy->64cy per kk); M kept in
// fp64 through K2 (no cvt for B operand at all); K3 scan vectorized to float4;
// K4 phase A processes 2 rows/wave with x held in registers, phase B unroll 8.

#define BK 16

__device__ __forceinline__ void mac16d(double (&acc)[4][4],
    const double a0, const double a1, const double a2, const double a3,
    const double b0, const double b1, const double b2, const double b3) {
  acc[0][0] += a0 * b0; acc[0][1] += a0 * b1; acc[0][2] += a0 * b2; acc[0][3] += a0 * b3;
  acc[1][0] += a1 * b0; acc[1][1] += a1 * b1; acc[1][2] += a1 * b2; acc[1][3] += a1 * b3;
  acc[2][0] += a2 * b0; acc[2][1] += a2 * b1; acc[2][2] += a2 * b2; acc[2][3] += a2 * b3;
  acc[3][0] += a3 * b0; acc[3][1] += a3 * b1; acc[3][2] += a3 * b2; acc[3][3] += a3 * b3;
}

__device__ __forceinline__ float dot4(const float4 a, const float4 b) {
  return a.x * b.x + a.y * b.y + a.z * b.z + a.w * b.w;
}

// ---------------- K1: M_slab(128x1024) = A_slab(128x512) @ B_slab(512x1024)
// slab s in [0,16): p = s>>3, h = s&7
// A[k][c] = keys[h,k,p,c]  (row stride 1024 floats)
// B[c][d] = Wq[p*4096 + h*512 + c][d]
__global__ __launch_bounds__(256) void fold_kernel(
    const float* __restrict__ keys, const float* __restrict__ Wq,
    double* __restrict__ M) {
  __shared__ double As[BK][68];   // transposed: As[c][krow]
  __shared__ double Bs[BK][68];   // direct:     Bs[c][d]
  const int s = blockIdx.z, p = s >> 3, h = s & 7;
  const float* A = keys + h * 131072 + p * 512;          // +k*1024 +c
  const float* B = Wq + (p * 4096 + h * 512) * 1024;     // +c*1024 +d
  double* C = M + (p * 1024 + h * 128) * 1024;           // +k*1024 +d
  const int row0 = blockIdx.y * 64;
  const int d0 = blockIdx.x * 64;
  const int t = threadIdx.x;
  const int tx = t & 15, ty = t >> 4;
  const int arow = t >> 2, ac4 = (t & 3) * 4;
  const int brow = t >> 4, bd4 = (t & 15) * 4;
  double acc[4][4] = {};
  for (int k0 = 0; k0 < 512; k0 += BK) {
    float4 a4 = *(const float4*)(A + (row0 + arow) * 1024 + k0 + ac4);
    float4 b4 = *(const float4*)(B + (k0 + brow) * 1024 + d0 + bd4);
    As[ac4 + 0][arow] = (double)a4.x; As[ac4 + 1][arow] = (double)a4.y;
    As[ac4 + 2][arow] = (double)a4.z; As[ac4 + 3][arow] = (double)a4.w;
    *(double2*)&Bs[brow][bd4 + 0] = make_double2((double)b4.x, (double)b4.y);
    *(double2*)&Bs[brow][bd4 + 2] = make_double2((double)b4.z, (double)b4.w);
    __syncthreads();
#pragma unroll
    for (int kk = 0; kk < BK; ++kk) {
      const double2 a01 = *(const double2*)&As[kk][ty * 4];
      const double2 a23 = *(const double2*)&As[kk][ty * 4 + 2];
      const double2 b01 = *(const double2*)&Bs[kk][tx * 4];
      const double2 b23 = *(const double2*)&Bs[kk][tx * 4 + 2];
      mac16d(acc, a01.x, a01.y, a23.x, a23.y, b01.x, b01.y, b23.x, b23.y);
    }
    __syncthreads();
  }
#pragma unroll
  for (int i = 0; i < 4; ++i) {
    double* cr = C + (row0 + ty * 4 + i) * 1024 + d0 + tx * 4;
    *(double2*)(cr + 0) = make_double2(acc[i][0], acc[i][1]);
    *(double2*)(cr + 2) = make_double2(acc[i][2], acc[i][3]);
  }
}

// ---------------- K2: sim[n][r] = sum_d x[n][d] * M[r][d]   (A @ B^T, B fp64)
__global__ __launch_bounds__(256) void sim_kernel(
    const float* __restrict__ x, const double* __restrict__ M,
    float* __restrict__ sim) {
  __shared__ double As[BK][68];   // As[k][n-local]
  __shared__ double Bs[BK][68];   // Bs[k][r-local]
  const int n0 = blockIdx.y * 64;
  const int r0 = blockIdx.x * 64;
  const int t = threadIdx.x;
  const int tx = t & 15, ty = t >> 4;
  const int arow = t >> 2, ak4 = (t & 3) * 4;
  double acc[4][4] = {};
  for (int k0 = 0; k0 < 1024; k0 += BK) {
    float4 a4 = *(const float4*)(x + (n0 + arow) * 1024 + k0 + ak4);
    const double* mrow = M + (r0 + arow) * 1024 + k0 + ak4;
    double2 b01 = *(const double2*)(mrow + 0);
    double2 b23 = *(const double2*)(mrow + 2);
    As[ak4 + 0][arow] = (double)a4.x; As[ak4 + 1][arow] = (double)a4.y;
    As[ak4 + 2][arow] = (double)a4.z; As[ak4 + 3][arow] = (double)a4.w;
    Bs[ak4 + 0][arow] = b01.x; Bs[ak4 + 1][arow] = b01.y;
    Bs[ak4 + 2][arow] = b23.x; Bs[ak4 + 3][arow] = b23.y;
    __syncthreads();
#pragma unroll
    for (int kk = 0; kk < BK; ++kk) {
      const double2 a01 = *(const double2*)&As[kk][ty * 4];
      const double2 a23 = *(const double2*)&As[kk][ty * 4 + 2];
      const double2 b01v = *(const double2*)&Bs[kk][tx * 4];
      const double2 b23v = *(const double2*)&Bs[kk][tx * 4 + 2];
      mac16d(acc, a01.x, a01.y, a23.x, a23.y, b01v.x, b01v.y, b23v.x, b23v.y);
    }
    __syncthreads();
  }
#pragma unroll
  for (int i = 0; i < 4; ++i) {
    float4 o = {(float)acc[i][0], (float)acc[i][1], (float)acc[i][2], (float)acc[i][3]};
    *(float4*)(sim + (n0 + ty * 4 + i) * 2048 + r0 + tx * 4) = o;
  }
}

// ---------------- K3: per (n,h) thread: top16(x), top16(y), staircase merge, softmax
__device__ __forceinline__ void insert16(float (&v)[16], int (&id)[16],
                                         float nv, int nid) {
  // stable: strictly-greater only => ties keep earlier index first (jax.lax.top_k)
  if (nv > v[15]) {
    v[15] = nv; id[15] = nid;
#pragma unroll
    for (int j = 15; j > 0; --j) {
      if (v[j] > v[j - 1]) {
        float tv = v[j]; v[j] = v[j - 1]; v[j - 1] = tv;
        int ti = id[j]; id[j] = id[j - 1]; id[j - 1] = ti;
      }
    }
  }
}

__global__ __launch_bounds__(256) void topk_kernel(
    const float* __restrict__ sim, int* __restrict__ rows,
    float* __restrict__ wts) {
  const int tid = blockIdx.x * 256 + threadIdx.x;  // 0..8191 = n*8+h
  const int n = tid >> 3, h = tid & 7;
  const float4* sx4 = (const float4*)(sim + n * 2048 + h * 128);  // p=0
  const float4* sy4 = sx4 + 256;                                  // p=1 (+1024 floats)
  float vx[16], vy[16]; int ix[16], iy[16];
#pragma unroll
  for (int j = 0; j < 16; ++j) { vx[j] = -1e30f; vy[j] = -1e30f; ix[j] = 0; iy[j] = 0; }
  for (int k = 0; k < 32; ++k) {
    const float4 a = sx4[k];
    const float4 b = sy4[k];
    insert16(vx, ix, a.x, k * 4 + 0); insert16(vx, ix, a.y, k * 4 + 1);
    insert16(vx, ix, a.z, k * 4 + 2); insert16(vx, ix, a.w, k * 4 + 3);
    insert16(vy, iy, b.x, k * 4 + 0); insert16(vy, iy, b.y, k * 4 + 1);
    insert16(vy, iy, b.z, k * 4 + 2); insert16(vy, iy, b.w, k * 4 + 3);
  }
  // cartesian top-16 of 256; only (i+1)*(j+1)<=16 can make the cut (dominance),
  // processed in flat-index order (i asc, j asc) for stable ties.
  constexpr int JMAX[16] = {16, 8, 5, 4, 3, 2, 2, 2, 1, 1, 1, 1, 1, 1, 1, 1};
  float cv[16]; int cid[16];
#pragma unroll
  for (int j = 0; j < 16; ++j) { cv[j] = -1e30f; cid[j] = 0; }
#pragma unroll
  for (int i = 0; i < 16; ++i) {
#pragma unroll
    for (int j = 0; j < 16; ++j) {
      if (j < JMAX[i]) {
        insert16(cv, cid, vx[i] + vy[j], ix[i] * 128 + iy[j]);
      }
    }
  }
  // softmax over the 16 selected scores (cv[0] is the max)
  float e[16], se = 0.f;
#pragma unroll
  for (int j = 0; j < 16; ++j) { e[j] = expf(cv[j] - cv[0]); se += e[j]; }
  const float inv = 1.0f / se;
#pragma unroll
  for (int j = 0; j < 16; ++j) {
    rows[tid * 16 + j] = h * 16384 + cid[j];
    wts[tid * 16 + j] = e[j] * inv;
  }
}

// ---------------- K4: one block per token. Phase A: g[i]=w*gelu(x.down[row_i]);
// Phase B: out[n] = sum_i g[i]*up[row_i]
__global__ __launch_bounds__(256) void gather_kernel(
    const float* __restrict__ x, const float* __restrict__ up,
    const float* __restrict__ down, const int* __restrict__ rows,
    const float* __restrict__ wts, float* __restrict__ out) {
  __shared__ float xs[1024];
  __shared__ float gs[128];
  __shared__ int rS[128];
  __shared__ float wS[128];
  const int n = blockIdx.x;
  const int t = threadIdx.x;
  ((float4*)xs)[t] = ((const float4*)(x + n * 1024))[t];
  if (t < 128) { rS[t] = rows[n * 128 + t]; wS[t] = wts[n * 128 + t]; }
  __syncthreads();
  const int wave = t >> 6, lane = t & 63;
  const float4* xp = (const float4*)xs;
  // x row held in registers: reused for 32 dot products per wave
  const float4 xv0 = xp[lane], xv1 = xp[lane + 64];
  const float4 xv2 = xp[lane + 128], xv3 = xp[lane + 192];
  // Phase A: 2 rows per wave per iteration (2x memory-level parallelism,
  // interleaved shuffle-reduce chains)
  for (int it = 0; it < 16; ++it) {
    const int i0 = it * 8 + wave * 2;
    const long r0 = rS[i0], r1 = rS[i0 + 1];
    const float4* dp0 = (const float4*)(down + r0 * 1024);
    const float4* dp1 = (const float4*)(down + r1 * 1024);
    const float4 d00 = dp0[lane], d01 = dp0[lane + 64];
    const float4 d02 = dp0[lane + 128], d03 = dp0[lane + 192];
    const float4 d10 = dp1[lane], d11 = dp1[lane + 64];
    const float4 d12 = dp1[lane + 128], d13 = dp1[lane + 192];
    float acc0 = dot4(d00, xv0) + dot4(d01, xv1) + dot4(d02, xv2) + dot4(d03, xv3);
    float acc1 = dot4(d10, xv0) + dot4(d11, xv1) + dot4(d12, xv2) + dot4(d13, xv3);
#pragma unroll
    for (int off = 32; off; off >>= 1) {
      acc0 += __shfl_down(acc0, off);
      acc1 += __shfl_down(acc1, off);
    }
    if (lane == 0) {
      const float g0 = 0.5f * acc0 * (1.0f + erff(acc0 * 0.70710678118654752f));
      const float g1 = 0.5f * acc1 * (1.0f + erff(acc1 * 0.70710678118654752f));
      gs[i0] = g0 * wS[i0];
      gs[i0 + 1] = g1 * wS[i0 + 1];
    }
  }
  __syncthreads();
  float4 a = {0.f, 0.f, 0.f, 0.f};
  const float4* upb = (const float4*)up;
#pragma unroll 8
  for (int i = 0; i < 128; ++i) {
    const long row = rS[i];
    const float g = gs[i];
    float4 u = upb[row * 256 + t];
    a.x += g * u.x; a.y += g * u.y; a.z += g * u.z; a.w += g * u.w;
  }
  ((float4*)out)[n * 256 + t] = a;
}

extern "C" void kernel_launch(void* const* d_in, const int* in_sizes, int n_in,
                              void* d_out, int out_size, void* d_ws, size_t ws_size,
                              hipStream_t stream) {
  const float* x = (const float*)d_in[0];
  const float* Wq = (const float*)d_in[1];
  const float* keys = (const float*)d_in[2];
  const float* up = (const float*)d_in[3];
  const float* down = (const float*)d_in[4];
  float* out = (float*)d_out;
  float* ws = (float*)d_ws;
  // workspace layout (floats):
  //   M double[2048*1024]  -> 4,194,304 floats
  //   sim float[1024*2048] -> 2,097,152 floats
  //   rows int[8192*16] | wts float[8192*16]
  double* M = (double*)ws;
  float* sim = ws + 4194304;
  int* rows = (int*)(ws + 6291456);
  float* wts = ws + 6422528;

  fold_kernel<<<dim3(16, 2, 16), 256, 0, stream>>>(keys, Wq, M);
  sim_kernel<<<dim3(32, 16, 1), 256, 0, stream>>>(x, M, sim);
  topk_kernel<<<32, 256, 0, stream>>>(sim, rows, wts);
  gather_kernel<<<1024, 256, 0, stream>>>(x, up, down, rows, wts, out);
}